// Round 1
// baseline (8741.418 us; speedup 1.0000x reference)
//
#include <hip/hip_runtime.h>
#include <hip/hip_bf16.h>
#include <math.h>

// ---------------------------------------------------------------------------
// Model dims (fixed by the reference)
// ---------------------------------------------------------------------------
#define T_LEN 512
#define LAT   1024
#define D_DIM 512
#define NH    8
#define HD    64
#define FF_D  2048
#define NL    8
#define CBD   256
#define NQ    16

// ---------------------------------------------------------------------------
// Gather: qf_pre[t,c] = emb_first[codes[0,t], c];
//         G[t, n*256+c] = emb_rest[n, codes[n+1,t], c]   (n in [0,15))
// ---------------------------------------------------------------------------
__global__ __launch_bounds__(256) void k_gather(const int* __restrict__ codes,
                                                const float* __restrict__ emb_first,
                                                const float* __restrict__ emb_rest,
                                                float* __restrict__ qf_pre,
                                                float* __restrict__ G) {
    int idx = blockIdx.x * 256 + threadIdx.x;       // < 512*16*256
    int c = idx & 255;
    int r = (idx >> 8) & 15;
    int t = idx >> 12;
    if (t >= T_LEN) return;
    if (r == 0) {
        int code = codes[t];                         // codes[:,0]
        qf_pre[t * 256 + c] = emb_first[code * 256 + c];
    } else {
        int n = r - 1;
        int code = codes[(n + 1) * T_LEN + t];
        G[t * 3840 + n * 256 + c] = emb_rest[(n * 2048 + code) * 256 + c];
    }
}

__global__ void k_bias_sum(const float* __restrict__ pr_b, float* __restrict__ out) {
    int d = blockIdx.x * 256 + threadIdx.x;
    if (d >= LAT) return;
    float s = 0.f;
    for (int n = 0; n < NQ - 1; n++) s += pr_b[n * LAT + d];
    out[d] = s;
}

// ---------------------------------------------------------------------------
// Tiled SGEMM: C[M,N] = epilogue(A[M,K] @ B[K,N])
// M%64==0, N%64==0, K%16==0 (true for all call sites).
// epilogue: +bias[col] (if bias), gelu (if flag), *scale[col] (if scale),
//           +res[row,col] (if res)
// ---------------------------------------------------------------------------
__global__ __launch_bounds__(256) void k_gemm(const float* __restrict__ A,
                                              const float* __restrict__ B,
                                              const float* __restrict__ bias,
                                              const float* __restrict__ res,
                                              const float* __restrict__ scale,
                                              float* __restrict__ C,
                                              int M, int N, int K, int gelu_flag) {
    __shared__ float As[64][17];
    __shared__ float Bs[16][64];
    int tid = threadIdx.x;
    int m0 = blockIdx.x * 64, n0 = blockIdx.y * 64;
    int tx = tid & 15, ty = tid >> 4;
    int ac = tid & 15, ar0 = tid >> 4;
    int bc = tid & 63, br0 = tid >> 6;
    float acc[4][4] = {};
    for (int k0 = 0; k0 < K; k0 += 16) {
#pragma unroll
        for (int i = 0; i < 4; i++)
            As[ar0 + 16 * i][ac] = A[(size_t)(m0 + ar0 + 16 * i) * K + k0 + ac];
#pragma unroll
        for (int i = 0; i < 4; i++)
            Bs[br0 + 4 * i][bc] = B[(size_t)(k0 + br0 + 4 * i) * N + n0 + bc];
        __syncthreads();
#pragma unroll
        for (int kk = 0; kk < 16; kk++) {
            float a[4], b[4];
#pragma unroll
            for (int i = 0; i < 4; i++) a[i] = As[ty * 4 + i][kk];
#pragma unroll
            for (int j = 0; j < 4; j++) b[j] = Bs[kk][tx * 4 + j];
#pragma unroll
            for (int i = 0; i < 4; i++)
#pragma unroll
                for (int j = 0; j < 4; j++) acc[i][j] += a[i] * b[j];
        }
        __syncthreads();
    }
#pragma unroll
    for (int i = 0; i < 4; i++) {
        int row = m0 + ty * 4 + i;
#pragma unroll
        for (int j = 0; j < 4; j++) {
            int col = n0 + tx * 4 + j;
            float v = acc[i][j];
            if (bias) v += bias[col];
            if (gelu_flag) v = 0.5f * v * (1.0f + erff(v * 0.70710678118654752440f));
            if (scale) v *= scale[col];
            if (res) v += res[(size_t)row * N + col];
            C[(size_t)row * N + col] = v;
        }
    }
}

// ---------------------------------------------------------------------------
// RMSNorm over rows of x[M,N]: y = x * rsqrt(mean(x^2)+1e-6) * g
// ---------------------------------------------------------------------------
__global__ __launch_bounds__(256) void k_rms(const float* __restrict__ x,
                                             const float* __restrict__ g,
                                             float* __restrict__ y, int N) {
    int row = blockIdx.x;
    const float* xr = x + (size_t)row * N;
    int tid = threadIdx.x;
    float s = 0.f;
    for (int i = tid; i < N; i += 256) { float v = xr[i]; s += v * v; }
#pragma unroll
    for (int off = 32; off; off >>= 1) s += __shfl_xor(s, off);
    __shared__ float red[4];
    if ((tid & 63) == 0) red[tid >> 6] = s;
    __syncthreads();
    s = red[0] + red[1] + red[2] + red[3];
    float r = 1.0f / sqrtf(s / (float)N + 1e-6f);
    for (int i = tid; i < N; i += 256) y[(size_t)row * N + i] = xr[i] * r * g[i];
}

// ---------------------------------------------------------------------------
// Fused qk-norm (RMS over HD=64 with gamma) + RoPE, in place.
// q layout [T, 512], head h at cols h*64..h*64+63. block=64 threads, grid=T*H
// ---------------------------------------------------------------------------
__global__ void k_qkrope(float* __restrict__ q, const float* __restrict__ g) {
    int bid = blockIdx.x;
    int t = bid >> 3, h = bid & 7;
    int d = threadIdx.x;                       // 0..63
    float* p = q + (size_t)t * D_DIM + h * HD;
    float val = p[d];
    float s = val * val;
#pragma unroll
    for (int off = 32; off; off >>= 1) s += __shfl_xor(s, off);
    float r = 1.0f / sqrtf(s * (1.0f / 64.0f) + 1e-6f);
    float y = val * r * g[d];
    int dm = d & 31;
    double inv = pow(10000.0, -(double)dm / 32.0);
    double ang = (double)t * inv;
    float c = (float)cos(ang);
    float sn = (float)sin(ang);
    float partner = __shfl_xor(y, 32);
    float out = (d < 32) ? (y * c - partner * sn) : (y * c + partner * sn);
    p[d] = out;
}

// ---------------------------------------------------------------------------
// Causal attention, one block per (t, h). q,k,v,o: [T, 512]
// ---------------------------------------------------------------------------
__global__ __launch_bounds__(256) void k_attn(const float* __restrict__ q,
                                              const float* __restrict__ k,
                                              const float* __restrict__ v,
                                              float* __restrict__ o) {
    int bid = blockIdx.x;
    int t = bid >> 3, h = bid & 7;
    __shared__ float qs[64];
    __shared__ float sc[T_LEN];
    __shared__ float red[8];
    int tid = threadIdx.x;
    if (tid < 64) qs[tid] = q[(size_t)t * D_DIM + h * HD + tid];
    __syncthreads();
    int nk = t + 1;
    for (int kk = tid; kk < nk; kk += 256) {
        const float* kr = k + (size_t)kk * D_DIM + h * HD;
        float dot = 0.f;
#pragma unroll
        for (int d = 0; d < HD; d++) dot += qs[d] * kr[d];
        sc[kk] = dot * 0.125f;
    }
    __syncthreads();
    float m = -3.4e38f;
    for (int i = tid; i < nk; i += 256) m = fmaxf(m, sc[i]);
#pragma unroll
    for (int off = 32; off; off >>= 1) m = fmaxf(m, __shfl_xor(m, off));
    if ((tid & 63) == 0) red[tid >> 6] = m;
    __syncthreads();
    m = fmaxf(fmaxf(red[0], red[1]), fmaxf(red[2], red[3]));
    float ssum = 0.f;
    for (int i = tid; i < nk; i += 256) { float e = expf(sc[i] - m); sc[i] = e; ssum += e; }
#pragma unroll
    for (int off = 32; off; off >>= 1) ssum += __shfl_xor(ssum, off);
    if ((tid & 63) == 0) red[4 + (tid >> 6)] = ssum;
    __syncthreads();
    ssum = red[4] + red[5] + red[6] + red[7];
    float inv = 1.0f / ssum;
    int d = tid & 63, part = tid >> 6;
    float a0 = 0.f;
    for (int i = part; i < nk; i += 4) a0 += sc[i] * v[(size_t)i * D_DIM + h * HD + d];
    __syncthreads();
    sc[part * 64 + d] = a0;
    __syncthreads();
    if (tid < 64) {
        float r = (sc[tid] + sc[64 + tid] + sc[128 + tid] + sc[192 + tid]) * inv;
        o[(size_t)t * D_DIM + h * HD + tid] = r;
    }
}

// ---------------------------------------------------------------------------
// Direct stride-1 conv: y[o,co] = b[co] + sum_{kk,ci} x[o+kk-pad_l, ci]*w[kk,ci,co]
// Cout multiple of 256. Each thread: one co, OPT=16 consecutive outputs.
// ---------------------------------------------------------------------------
template <int K>
__global__ __launch_bounds__(256) void k_conv(const float* __restrict__ x,
                                              const float* __restrict__ w,
                                              const float* __restrict__ bias,
                                              float* __restrict__ y,
                                              int in_len, int out_len, int Cin, int Cout,
                                              int pad_l, int elu_out) {
    constexpr int OPT = 16;
    int co = blockIdx.y * 256 + threadIdx.x;
    int o0 = blockIdx.x * OPT;
    float acc[OPT];
    float bv = bias[co];
#pragma unroll
    for (int m = 0; m < OPT; m++) acc[m] = bv;
    for (int ci = 0; ci < Cin; ci++) {
        float xv[OPT + K - 1];
#pragma unroll
        for (int i = 0; i < OPT + K - 1; i++) {
            int t = o0 - pad_l + i;
            xv[i] = (t >= 0 && t < in_len) ? x[(size_t)t * Cin + ci] : 0.f;
        }
#pragma unroll
        for (int kk = 0; kk < K; kk++) {
            float wv = w[(size_t)(kk * Cin + ci) * Cout + co];
#pragma unroll
            for (int m = 0; m < OPT; m++) acc[m] += xv[m + kk] * wv;
        }
    }
#pragma unroll
    for (int m = 0; m < OPT; m++) {
        int o = o0 + m;
        if (o < out_len) {
            float v = acc[m];
            if (elu_out) v = v > 0.f ? v : expm1f(v);
            y[(size_t)o * Cout + co] = v;
        }
    }
}

// ---------------------------------------------------------------------------
// Transposed conv (K = 2*s exactly, SAME, jax conv_transpose semantics):
// phase p = o % s, q = o / s:
//   out[q*s+p, co] = b[co] + x[q+cp]·w[kk0] + x[q+cp+1]·w[kk0+s]
//   kk0 = (pad_a - p) mod s,  cp = (p + kk0 - pad_a)/s
// grid: (ceil(in_len/(QG*QT)), s, Cout>=256 ? Cout/256 : 1)
// ---------------------------------------------------------------------------
template <int QT>
__global__ __launch_bounds__(256) void k_convT(const float* __restrict__ x,
                                               const float* __restrict__ w,
                                               const float* __restrict__ bias,
                                               float* __restrict__ y,
                                               int in_len, int Cin, int Cout,
                                               int s, int pad_a, int elu_out) {
    int tid = threadIdx.x;
    int p = blockIdx.y;
    int kk0 = (pad_a - p) % s;
    if (kk0 < 0) kk0 += s;
    int cp = (p + kk0 - pad_a) / s;
    int co, qsub, QG;
    if (Cout >= 256) { co = blockIdx.z * 256 + tid; qsub = 0; QG = 1; }
    else { co = tid % Cout; qsub = tid / Cout; QG = 256 / Cout; }
    int qbase = (blockIdx.x * QG + qsub) * QT;
    float acc[QT];
    float bv = bias[co];
#pragma unroll
    for (int m = 0; m < QT; m++) acc[m] = bv;
    const float* w0p = w + (size_t)(kk0 * Cin) * Cout + co;
    const float* w1p = w + (size_t)((kk0 + s) * Cin) * Cout + co;
    for (int ci = 0; ci < Cin; ci++) {
        float w0 = w0p[(size_t)ci * Cout];
        float w1 = w1p[(size_t)ci * Cout];
        float xv[QT + 1];
#pragma unroll
        for (int i = 0; i <= QT; i++) {
            int ii = qbase + i + cp;
            xv[i] = (ii >= 0 && ii < in_len) ? x[(size_t)ii * Cin + ci] : 0.f;
        }
#pragma unroll
        for (int m = 0; m < QT; m++) acc[m] += xv[m] * w0 + xv[m + 1] * w1;
    }
#pragma unroll
    for (int m = 0; m < QT; m++) {
        int qq = qbase + m;
        if (qq < in_len) {
            float v = acc[m];
            if (elu_out) v = v > 0.f ? v : expm1f(v);
            y[((size_t)qq * s + p) * Cout + co] = v;
        }
    }
}

// ---------------------------------------------------------------------------
// Final conv: Cin=32, Cout=1, K=7 SAME, clip to [-1,1]. Block = 256 outputs.
// ---------------------------------------------------------------------------
__global__ __launch_bounds__(256) void k_conv_fin(const float* __restrict__ x,
                                                  const float* __restrict__ w,
                                                  const float* __restrict__ b,
                                                  float* __restrict__ y, int n) {
    __shared__ float xs[262 * 33];
    __shared__ float wsm[224];
    int tid = threadIdx.x;
    int o0 = blockIdx.x * 256;
    for (int i = tid; i < 262 * 32; i += 256) {
        int r = i >> 5, c = i & 31;
        int t = o0 - 3 + r;
        xs[r * 33 + c] = (t >= 0 && t < n) ? x[(size_t)t * 32 + c] : 0.f;
    }
    if (tid < 224) wsm[tid] = w[tid];
    __syncthreads();
    float acc = b[0];
#pragma unroll
    for (int kk = 0; kk < 7; kk++)
#pragma unroll
        for (int ci = 0; ci < 32; ci++)
            acc += xs[(tid + kk) * 33 + ci] * wsm[kk * 32 + ci];
    y[o0 + tid] = fminf(fmaxf(acc, -1.f), 1.f);
}

// ---------------------------------------------------------------------------
// Host launch
// ---------------------------------------------------------------------------
static inline void gemm(hipStream_t st, const float* A, const float* B, const float* bias,
                        const float* res, const float* scale, float* C,
                        int M, int N, int K, int gelu) {
    dim3 g(M / 64, N / 64);
    k_gemm<<<g, 256, 0, st>>>(A, B, bias, res, scale, C, M, N, K, gelu);
}

extern "C" void kernel_launch(void* const* d_in, const int* in_sizes, int n_in,
                              void* d_out, int out_size, void* d_ws, size_t ws_size,
                              hipStream_t stream) {
    int i = 0;
    const int*   codes     = (const int*)  d_in[i++]; // 0
    const float* emb_first = (const float*)d_in[i++]; // 1
    const float* pf_w      = (const float*)d_in[i++];
    const float* pf_b      = (const float*)d_in[i++];
    const float* fo_w      = (const float*)d_in[i++];
    const float* fo_b      = (const float*)d_in[i++];
    const float* emb_rest  = (const float*)d_in[i++]; // 6
    const float* pr_w      = (const float*)d_in[i++];
    const float* pr_b      = (const float*)d_in[i++];
    const float* ro_w      = (const float*)d_in[i++];
    const float* ro_b      = (const float*)d_in[i++]; // 10
    const float* pre_w     = (const float*)d_in[i++];
    const float* pre_b     = (const float*)d_in[i++];
    const float* in_w      = (const float*)d_in[i++];
    const float* in_b      = (const float*)d_in[i++];
    const float* ln1       = (const float*)d_in[i++]; // 15
    const float* qw        = (const float*)d_in[i++];
    const float* kw        = (const float*)d_in[i++];
    const float* vw        = (const float*)d_in[i++];
    const float* ow        = (const float*)d_in[i++];
    const float* qn        = (const float*)d_in[i++]; // 20
    const float* kn        = (const float*)d_in[i++];
    const float* ls_a      = (const float*)d_in[i++];
    const float* ln2       = (const float*)d_in[i++];
    const float* w1        = (const float*)d_in[i++];
    const float* w2        = (const float*)d_in[i++]; // 25
    const float* ls_m      = (const float*)d_in[i++];
    const float* fn_w      = (const float*)d_in[i++];
    const float* out_w     = (const float*)d_in[i++];
    const float* out_b     = (const float*)d_in[i++];
    const float* up_w      = (const float*)d_in[i++]; // 30
    const float* up_b      = (const float*)d_in[i++];
    const float* dec0_w    = (const float*)d_in[i++];
    const float* dec0_b    = (const float*)d_in[i++];
    const float* dw1       = (const float*)d_in[i++];
    const float* db1       = (const float*)d_in[i++]; // 35
    const float* dw2       = (const float*)d_in[i++];
    const float* db2       = (const float*)d_in[i++];
    const float* dw3       = (const float*)d_in[i++];
    const float* db3       = (const float*)d_in[i++];
    const float* dw4       = (const float*)d_in[i++]; // 40
    const float* db4       = (const float*)d_in[i++];
    const float* fin_w     = (const float*)d_in[i++];
    const float* fin_b     = (const float*)d_in[i++];

    float* ws = (float*)d_ws;
    float* outp = (float*)d_out;

    // Workspace layout (floats). t4 (31457280) aliases the early region;
    // all early buffers (incl. t1/t2) are dead before dw4 writes t4.
    float* qf_pre   = ws;                // 131072
    float* G        = ws + 131072;       // 1966080
    float* qf       = ws + 2097152;      // 524288
    float* tA       = ws + 2621440;      // 524288
    float* hidden   = ws + 3145728;      // 524288
    float* conv_out = ws + 3670016;      // 524288
    float* h        = ws + 4194304;      // 262144
    float* x        = ws + 4456448;      // 262144
    float* qb       = ws + 4718592;      // 262144
    float* kb       = ws + 4980736;      // 262144
    float* vb       = ws + 5242880;      // 262144
    float* attnb    = ws + 5505024;      // 262144
    float* ff       = ws + 5767168;      // 1048576
    float* houtp    = ws + 6815744;      // 524288
    float* up_out   = ws + 7340032;      // 1048576
    float* dec0_out = ws + 8388608;      // 524288
    float* bias_sum = ws + 8912896;      // 1024
    float* t1       = ws + 8913920;      // 2097152  (dead before t4 written)
    float* t2       = ws + 11011072;     // 6291456  (dead before t4 written)
    float* t3       = ws + 31457280;     // 15728640
    float* t4       = ws;                // 31457280 (aliases early region)

    // --- RVQ decode ---
    k_gather<<<8192, 256, 0, stream>>>(codes, emb_first, emb_rest, qf_pre, G);
    k_bias_sum<<<4, 256, 0, stream>>>(pr_b, bias_sum);
    gemm(stream, qf_pre, pf_w, pf_b, nullptr, nullptr, tA, 512, 1024, 256, 0);
    gemm(stream, tA, fo_w, fo_b, nullptr, nullptr, qf, 512, 1024, 1024, 0);
    gemm(stream, G, pr_w, bias_sum, nullptr, nullptr, tA, 512, 1024, 3840, 0);
    gemm(stream, tA, ro_w, ro_b, qf, nullptr, hidden, 512, 1024, 1024, 0); // + qf residual

    // --- causal pre-conv (k=3, left pad 2) ---
    k_conv<3><<<dim3(512 / 16, LAT / 256), 256, 0, stream>>>(
        hidden, pre_w, pre_b, conv_out, 512, 512, LAT, LAT, 2, 0);

    // --- transformer input proj ---
    gemm(stream, conv_out, in_w, in_b, nullptr, nullptr, h, 512, 512, 1024, 0);

    // --- 8 transformer layers ---
    for (int l = 0; l < NL; l++) {
        const float* qw_l = qw + (size_t)l * D_DIM * D_DIM;
        const float* kw_l = kw + (size_t)l * D_DIM * D_DIM;
        const float* vw_l = vw + (size_t)l * D_DIM * D_DIM;
        const float* ow_l = ow + (size_t)l * D_DIM * D_DIM;
        const float* w1_l = w1 + (size_t)l * D_DIM * FF_D;
        const float* w2_l = w2 + (size_t)l * FF_D * D_DIM;

        k_rms<<<512, 256, 0, stream>>>(h, ln1 + l * D_DIM, x, D_DIM);
        gemm(stream, x, qw_l, nullptr, nullptr, nullptr, qb, 512, 512, 512, 0);
        gemm(stream, x, kw_l, nullptr, nullptr, nullptr, kb, 512, 512, 512, 0);
        gemm(stream, x, vw_l, nullptr, nullptr, nullptr, vb, 512, 512, 512, 0);
        k_qkrope<<<T_LEN * NH, 64, 0, stream>>>(qb, qn + l * HD);
        k_qkrope<<<T_LEN * NH, 64, 0, stream>>>(kb, kn + l * HD);
        k_attn<<<T_LEN * NH, 256, 0, stream>>>(qb, kb, vb, attnb);
        gemm(stream, attnb, ow_l, nullptr, h, ls_a + l * D_DIM, h, 512, 512, 512, 0);
        k_rms<<<512, 256, 0, stream>>>(h, ln2 + l * D_DIM, x, D_DIM);
        gemm(stream, x, w1_l, nullptr, nullptr, nullptr, ff, 512, 2048, 512, 1); // gelu
        gemm(stream, ff, w2_l, nullptr, h, ls_m + l * D_DIM, h, 512, 512, 2048, 0);
    }

    // --- final norm + out proj ---
    k_rms<<<512, 256, 0, stream>>>(h, fn_w, x, D_DIM);
    gemm(stream, x, out_w, out_b, nullptr, nullptr, houtp, 512, 1024, 512, 0);

    // --- upsample x2 convT (k=4,s=2,pad_a=2), elu fused on output ---
    k_convT<8><<<dim3(512 / 8, 2, 4), 256, 0, stream>>>(
        houtp, up_w, up_b, up_out, 512, 1024, 1024, 2, 2, 1);

    // --- dec0 conv k=7 SAME, elu out ---
    k_conv<7><<<dim3(1024 / 16, 512 / 256), 256, 0, stream>>>(
        up_out, dec0_w, dec0_b, dec0_out, 1024, 1024, 1024, 512, 3, 1);

    // --- SEANet convT chain (K=2s each), elu fused on outputs ---
    k_convT<8><<<dim3(1024 / 8, 8, 1), 256, 0, stream>>>(
        dec0_out, dw1, db1, t1, 1024, 512, 256, 8, 11, 1);
    k_convT<8><<<dim3(8192 / 16, 6, 1), 256, 0, stream>>>(
        t1, dw2, db2, t2, 8192, 256, 128, 6, 8, 1);
    k_convT<8><<<dim3(49152 / 32, 5, 1), 256, 0, stream>>>(
        t2, dw3, db3, t3, 49152, 128, 64, 5, 7, 1);
    k_convT<8><<<dim3(245760 / 64, 4, 1), 256, 0, stream>>>(
        t3, dw4, db4, t4, 245760, 64, 32, 4, 5, 1);

    // --- final conv k=7 SAME, Cin=32 -> 1, clip ---
    k_conv_fin<<<983040 / 256, 256, 0, stream>>>(t4, fin_w, fin_b, outp, 983040);
}

// Round 2
// 6302.555 us; speedup vs baseline: 1.3870x; 1.3870x over previous
//
#include <hip/hip_runtime.h>
#include <hip/hip_bf16.h>
#include <math.h>

#define T_LEN 512
#define LAT   1024
#define D_DIM 512
#define NH    8
#define HD    64
#define FF_D  2048
#define NL    8
#define NQ    16

// ---------------------------------------------------------------------------
// Gathers
// ---------------------------------------------------------------------------
__global__ __launch_bounds__(256) void k_gather(const int* __restrict__ codes,
                                                const float* __restrict__ emb_first,
                                                const float* __restrict__ emb_rest,
                                                float* __restrict__ qf_pre,
                                                float* __restrict__ G) {
    int idx = blockIdx.x * 256 + threadIdx.x;
    int c = idx & 255;
    int r = (idx >> 8) & 15;
    int t = idx >> 12;
    if (t >= T_LEN) return;
    if (r == 0) {
        int code = codes[t];
        qf_pre[t * 256 + c] = emb_first[code * 256 + c];
    } else {
        int n = r - 1;
        int code = codes[(n + 1) * T_LEN + t];
        G[t * 3840 + n * 256 + c] = emb_rest[(n * 2048 + code) * 256 + c];
    }
}

__global__ void k_bias_sum(const float* __restrict__ pr_b, float* __restrict__ out) {
    int d = blockIdx.x * 256 + threadIdx.x;
    if (d >= LAT) return;
    float s = 0.f;
    for (int n = 0; n < NQ - 1; n++) s += pr_b[n * LAT + d];
    out[d] = s;
}

// ---------------------------------------------------------------------------
// im2col: y[t, kk*C + c] = x[t-pad_l+kk, c]  (zero outside)
// ---------------------------------------------------------------------------
__global__ __launch_bounds__(256) void k_im2col(const float* __restrict__ x,
                                                float* __restrict__ y,
                                                int T, int C, int K, int pad_l) {
    int idx = blockIdx.x * 256 + threadIdx.x;
    if (idx >= T * K * C) return;
    int c = idx % C;
    int rest = idx / C;
    int kk = rest % K;
    int t = rest / K;
    int src = t - pad_l + kk;
    y[idx] = (src >= 0 && src < T) ? x[(size_t)src * C + c] : 0.f;
}

// ---------------------------------------------------------------------------
// Tiled SGEMM body. Tile TM x 64, 256 threads, K-step 16, k-major As (both
// fragment reads are contiguous -> b128/b64). act: 0 none, 1 gelu, 2 elu.
// ---------------------------------------------------------------------------
template <int TM>
__device__ __forceinline__ void gemm_body(const float* __restrict__ A,
                                          const float* __restrict__ B,
                                          const float* __restrict__ bias,
                                          const float* __restrict__ res,
                                          const float* __restrict__ scale,
                                          float* __restrict__ C,
                                          int N, int K, int act, int m0, int n0) {
    __shared__ float As[16][TM + 4];
    __shared__ float Bs[16][64];
    constexpr int RM = TM / 16;          // rows per thread (4 or 2)
    constexpr int AR = TM * 16 / 256;    // A elems per thread
    int tid = threadIdx.x;
    int tx = tid & 15, ty = tid >> 4;
    int bc = tid & 63, br0 = tid >> 6;
    float acc[RM][4] = {};
    for (int k0 = 0; k0 < K; k0 += 16) {
#pragma unroll
        for (int i = 0; i < AR; i++) {
            int idx = tid + 256 * i;
            int row = idx >> 4, kk = idx & 15;
            As[kk][row] = A[(size_t)(m0 + row) * K + k0 + kk];
        }
#pragma unroll
        for (int i = 0; i < 4; i++)
            Bs[br0 + 4 * i][bc] = B[(size_t)(k0 + br0 + 4 * i) * N + n0 + bc];
        __syncthreads();
#pragma unroll
        for (int kk = 0; kk < 16; kk++) {
            float a[RM], b[4];
#pragma unroll
            for (int i = 0; i < RM; i++) a[i] = As[kk][ty * RM + i];
#pragma unroll
            for (int j = 0; j < 4; j++) b[j] = Bs[kk][tx * 4 + j];
#pragma unroll
            for (int i = 0; i < RM; i++)
#pragma unroll
                for (int j = 0; j < 4; j++) acc[i][j] += a[i] * b[j];
        }
        __syncthreads();
    }
#pragma unroll
    for (int i = 0; i < RM; i++) {
        int row = m0 + ty * RM + i;
#pragma unroll
        for (int j = 0; j < 4; j++) {
            int col = n0 + tx * 4 + j;
            float v = acc[i][j];
            if (bias) v += bias[col];
            if (act == 1) v = 0.5f * v * (1.0f + erff(v * 0.70710678118654752440f));
            else if (act == 2) v = v > 0.f ? v : expm1f(v);
            if (scale) v *= scale[col];
            if (res) v += res[(size_t)row * N + col];
            C[(size_t)row * N + col] = v;
        }
    }
}

template <int TM>
__global__ __launch_bounds__(256) void k_gemm(const float* __restrict__ A,
                                              const float* __restrict__ B,
                                              const float* __restrict__ bias,
                                              const float* __restrict__ res,
                                              const float* __restrict__ scale,
                                              float* __restrict__ C,
                                              int N, int K, int act) {
    gemm_body<TM>(A, B, bias, res, scale, C, N, K, act,
                  blockIdx.x * TM, blockIdx.y * 64);
}

// Fused QKV: one dispatch, blockIdx.z selects weight/output.
__global__ __launch_bounds__(256) void k_gemm_qkv(const float* __restrict__ A,
                                                  const float* __restrict__ B0,
                                                  const float* __restrict__ B1,
                                                  const float* __restrict__ B2,
                                                  float* __restrict__ C0,
                                                  float* __restrict__ C1,
                                                  float* __restrict__ C2,
                                                  int N, int K) {
    const float* B = blockIdx.z == 0 ? B0 : (blockIdx.z == 1 ? B1 : B2);
    float* C = blockIdx.z == 0 ? C0 : (blockIdx.z == 1 ? C1 : C2);
    gemm_body<32>(A, B, nullptr, nullptr, nullptr, C, N, K, 0,
                  blockIdx.x * 32, blockIdx.y * 64);
}

// ---------------------------------------------------------------------------
// RMSNorm rows of x[M,N]
// ---------------------------------------------------------------------------
__global__ __launch_bounds__(256) void k_rms(const float* __restrict__ x,
                                             const float* __restrict__ g,
                                             float* __restrict__ y, int N) {
    int row = blockIdx.x;
    const float* xr = x + (size_t)row * N;
    int tid = threadIdx.x;
    float s = 0.f;
    for (int i = tid; i < N; i += 256) { float v = xr[i]; s += v * v; }
#pragma unroll
    for (int off = 32; off; off >>= 1) s += __shfl_xor(s, off);
    __shared__ float red[4];
    if ((tid & 63) == 0) red[tid >> 6] = s;
    __syncthreads();
    s = red[0] + red[1] + red[2] + red[3];
    float r = 1.0f / sqrtf(s / (float)N + 1e-6f);
    for (int i = tid; i < N; i += 256) y[(size_t)row * N + i] = xr[i] * r * g[i];
}

// ---------------------------------------------------------------------------
// Fused qk-norm + RoPE for q AND k in one dispatch (blockIdx.y picks buffer)
// ---------------------------------------------------------------------------
__global__ void k_qkrope2(float* __restrict__ q, float* __restrict__ k,
                          const float* __restrict__ gq, const float* __restrict__ gk) {
    int bid = blockIdx.x;
    int t = bid >> 3, h = bid & 7;
    int d = threadIdx.x;
    float* p = (blockIdx.y == 0 ? q : k) + (size_t)t * D_DIM + h * HD;
    const float* g = blockIdx.y == 0 ? gq : gk;
    float val = p[d];
    float s = val * val;
#pragma unroll
    for (int off = 32; off; off >>= 1) s += __shfl_xor(s, off);
    float r = 1.0f / sqrtf(s * (1.0f / 64.0f) + 1e-6f);
    float y = val * r * g[d];
    int dm = d & 31;
    double inv = pow(10000.0, -(double)dm / 32.0);
    double ang = (double)t * inv;
    float c = (float)cos(ang);
    float sn = (float)sin(ang);
    float partner = __shfl_xor(y, 32);
    float out = (d < 32) ? (y * c - partner * sn) : (y * c + partner * sn);
    p[d] = out;
}

// ---------------------------------------------------------------------------
// Causal attention, one block per (t, h)
// ---------------------------------------------------------------------------
__global__ __launch_bounds__(256) void k_attn(const float* __restrict__ q,
                                              const float* __restrict__ k,
                                              const float* __restrict__ v,
                                              float* __restrict__ o) {
    int bid = blockIdx.x;
    int t = bid >> 3, h = bid & 7;
    __shared__ float qs[64];
    __shared__ float sc[T_LEN];
    __shared__ float red[8];
    int tid = threadIdx.x;
    if (tid < 64) qs[tid] = q[(size_t)t * D_DIM + h * HD + tid];
    __syncthreads();
    int nk = t + 1;
    for (int kk = tid; kk < nk; kk += 256) {
        const float* kr = k + (size_t)kk * D_DIM + h * HD;
        float dot = 0.f;
#pragma unroll
        for (int d = 0; d < HD; d++) dot += qs[d] * kr[d];
        sc[kk] = dot * 0.125f;
    }
    __syncthreads();
    float m = -3.4e38f;
    for (int i = tid; i < nk; i += 256) m = fmaxf(m, sc[i]);
#pragma unroll
    for (int off = 32; off; off >>= 1) m = fmaxf(m, __shfl_xor(m, off));
    if ((tid & 63) == 0) red[tid >> 6] = m;
    __syncthreads();
    m = fmaxf(fmaxf(red[0], red[1]), fmaxf(red[2], red[3]));
    float ssum = 0.f;
    for (int i = tid; i < nk; i += 256) { float e = expf(sc[i] - m); sc[i] = e; ssum += e; }
#pragma unroll
    for (int off = 32; off; off >>= 1) ssum += __shfl_xor(ssum, off);
    if ((tid & 63) == 0) red[4 + (tid >> 6)] = ssum;
    __syncthreads();
    ssum = red[4] + red[5] + red[6] + red[7];
    float inv = 1.0f / ssum;
    int d = tid & 63, part = tid >> 6;
    float a0 = 0.f;
    for (int i = part; i < nk; i += 4) a0 += sc[i] * v[(size_t)i * D_DIM + h * HD + d];
    __syncthreads();
    sc[part * 64 + d] = a0;
    __syncthreads();
    if (tid < 64) {
        float r = (sc[tid] + sc[64 + tid] + sc[128 + tid] + sc[192 + tid]) * inv;
        o[(size_t)t * D_DIM + h * HD + tid] = r;
    }
}

// ---------------------------------------------------------------------------
// Transposed conv (K = 2*s), phase-decomposed into 2-tap convs
// ---------------------------------------------------------------------------
template <int QT>
__global__ __launch_bounds__(256) void k_convT(const float* __restrict__ x,
                                               const float* __restrict__ w,
                                               const float* __restrict__ bias,
                                               float* __restrict__ y,
                                               int in_len, int Cin, int Cout,
                                               int s, int pad_a, int elu_out) {
    int tid = threadIdx.x;
    int p = blockIdx.y;
    int kk0 = (pad_a - p) % s;
    if (kk0 < 0) kk0 += s;
    int cp = (p + kk0 - pad_a) / s;
    int co, qsub, QG;
    if (Cout >= 256) { co = blockIdx.z * 256 + tid; qsub = 0; QG = 1; }
    else { co = tid % Cout; qsub = tid / Cout; QG = 256 / Cout; }
    int qbase = (blockIdx.x * QG + qsub) * QT;
    float acc[QT];
    float bv = bias[co];
#pragma unroll
    for (int m = 0; m < QT; m++) acc[m] = bv;
    const float* w0p = w + (size_t)(kk0 * Cin) * Cout + co;
    const float* w1p = w + (size_t)((kk0 + s) * Cin) * Cout + co;
    for (int ci = 0; ci < Cin; ci++) {
        float w0 = w0p[(size_t)ci * Cout];
        float w1 = w1p[(size_t)ci * Cout];
        float xv[QT + 1];
#pragma unroll
        for (int i = 0; i <= QT; i++) {
            int ii = qbase + i + cp;
            xv[i] = (ii >= 0 && ii < in_len) ? x[(size_t)ii * Cin + ci] : 0.f;
        }
#pragma unroll
        for (int m = 0; m < QT; m++) acc[m] += xv[m] * w0 + xv[m + 1] * w1;
    }
#pragma unroll
    for (int m = 0; m < QT; m++) {
        int qq = qbase + m;
        if (qq < in_len) {
            float v = acc[m];
            if (elu_out) v = v > 0.f ? v : expm1f(v);
            y[((size_t)qq * s + p) * Cout + co] = v;
        }
    }
}

// ---------------------------------------------------------------------------
// Final conv: Cin=32 -> 1, K=7 SAME, clip
// ---------------------------------------------------------------------------
__global__ __launch_bounds__(256) void k_conv_fin(const float* __restrict__ x,
                                                  const float* __restrict__ w,
                                                  const float* __restrict__ b,
                                                  float* __restrict__ y, int n) {
    __shared__ float xs[262 * 33];
    __shared__ float wsm[224];
    int tid = threadIdx.x;
    int o0 = blockIdx.x * 256;
    for (int i = tid; i < 262 * 32; i += 256) {
        int r = i >> 5, c = i & 31;
        int t = o0 - 3 + r;
        xs[r * 33 + c] = (t >= 0 && t < n) ? x[(size_t)t * 32 + c] : 0.f;
    }
    if (tid < 224) wsm[tid] = w[tid];
    __syncthreads();
    float acc = b[0];
#pragma unroll
    for (int kk = 0; kk < 7; kk++)
#pragma unroll
        for (int ci = 0; ci < 32; ci++)
            acc += xs[(tid + kk) * 33 + ci] * wsm[kk * 32 + ci];
    y[o0 + tid] = fminf(fmaxf(acc, -1.f), 1.f);
}

// ---------------------------------------------------------------------------
// Host launch
// ---------------------------------------------------------------------------
static inline void gemm64(hipStream_t st, const float* A, const float* B, const float* bias,
                          const float* res, const float* scale, float* C,
                          int M, int N, int K, int act) {
    k_gemm<64><<<dim3(M / 64, N / 64), 256, 0, st>>>(A, B, bias, res, scale, C, N, K, act);
}
static inline void gemm32(hipStream_t st, const float* A, const float* B, const float* bias,
                          const float* res, const float* scale, float* C,
                          int M, int N, int K, int act) {
    k_gemm<32><<<dim3(M / 32, N / 64), 256, 0, st>>>(A, B, bias, res, scale, C, N, K, act);
}

extern "C" void kernel_launch(void* const* d_in, const int* in_sizes, int n_in,
                              void* d_out, int out_size, void* d_ws, size_t ws_size,
                              hipStream_t stream) {
    int i = 0;
    const int*   codes     = (const int*)  d_in[i++];
    const float* emb_first = (const float*)d_in[i++];
    const float* pf_w      = (const float*)d_in[i++];
    const float* pf_b      = (const float*)d_in[i++];
    const float* fo_w      = (const float*)d_in[i++];
    const float* fo_b      = (const float*)d_in[i++];
    const float* emb_rest  = (const float*)d_in[i++];
    const float* pr_w      = (const float*)d_in[i++];
    const float* pr_b      = (const float*)d_in[i++];
    const float* ro_w      = (const float*)d_in[i++];
    const float* ro_b      = (const float*)d_in[i++];
    const float* pre_w     = (const float*)d_in[i++];
    const float* pre_b     = (const float*)d_in[i++];
    const float* in_w      = (const float*)d_in[i++];
    const float* in_b      = (const float*)d_in[i++];
    const float* ln1       = (const float*)d_in[i++];
    const float* qw        = (const float*)d_in[i++];
    const float* kw        = (const float*)d_in[i++];
    const float* vw        = (const float*)d_in[i++];
    const float* ow        = (const float*)d_in[i++];
    const float* qn        = (const float*)d_in[i++];
    const float* kn        = (const float*)d_in[i++];
    const float* ls_a      = (const float*)d_in[i++];
    const float* ln2       = (const float*)d_in[i++];
    const float* w1        = (const float*)d_in[i++];
    const float* w2        = (const float*)d_in[i++];
    const float* ls_m      = (const float*)d_in[i++];
    const float* fn_w      = (const float*)d_in[i++];
    const float* out_w     = (const float*)d_in[i++];
    const float* out_b     = (const float*)d_in[i++];
    const float* up_w      = (const float*)d_in[i++];
    const float* up_b      = (const float*)d_in[i++];
    const float* dec0_w    = (const float*)d_in[i++];
    const float* dec0_b    = (const float*)d_in[i++];
    const float* dw1       = (const float*)d_in[i++];
    const float* db1       = (const float*)d_in[i++];
    const float* dw2       = (const float*)d_in[i++];
    const float* db2       = (const float*)d_in[i++];
    const float* dw3       = (const float*)d_in[i++];
    const float* db3       = (const float*)d_in[i++];
    const float* dw4       = (const float*)d_in[i++];
    const float* db4       = (const float*)d_in[i++];
    const float* fin_w     = (const float*)d_in[i++];
    const float* fin_b     = (const float*)d_in[i++];

    float* ws = (float*)d_ws;
    float* outp = (float*)d_out;

    // Workspace layout (floats)
    float* qf_pre   = ws;                // 131072
    float* G        = ws + 131072;       // 1966080
    float* qf       = ws + 2097152;      // 524288
    float* tA       = ws + 2621440;      // 524288
    float* hidden   = ws + 3145728;      // 524288
    float* conv_out = ws + 3670016;      // 524288
    float* h        = ws + 4194304;      // 262144
    float* x        = ws + 4456448;      // 262144
    float* qb       = ws + 4718592;      // 262144
    float* kb       = ws + 4980736;      // 262144
    float* vb       = ws + 5242880;      // 262144
    float* attnb    = ws + 5505024;      // 262144
    float* ff       = ws + 5767168;      // 1048576
    float* houtp    = ws + 6815744;      // 524288
    float* up_out   = ws + 7340032;      // 1048576
    float* dec0_out = ws + 8388608;      // 524288
    float* bias_sum = ws + 8912896;      // 1024
    float* t1       = ws + 8913920;      // 2097152
    float* t2       = ws + 11011072;     // 6291456 -> ends 17302528
    float* ic1      = ws + 17302528;     // 1572864 -> ends 18875392
    float* ic2      = ws + 18875392;     // 7340032 -> ends 26215424
    float* t3       = ws + 31457280;     // 15728640 -> ends 47185920
    float* t4       = ws;                // 31457280 (aliases all early bufs; they're dead)

    // --- RVQ decode ---
    k_gather<<<8192, 256, 0, stream>>>(codes, emb_first, emb_rest, qf_pre, G);
    k_bias_sum<<<4, 256, 0, stream>>>(pr_b, bias_sum);
    gemm64(stream, qf_pre, pf_w, pf_b, nullptr, nullptr, tA, 512, 1024, 256, 0);
    gemm64(stream, tA, fo_w, fo_b, nullptr, nullptr, qf, 512, 1024, 1024, 0);
    gemm64(stream, G, pr_w, bias_sum, nullptr, nullptr, tA, 512, 1024, 3840, 0);
    gemm64(stream, tA, ro_w, ro_b, qf, nullptr, hidden, 512, 1024, 1024, 0);

    // --- causal pre-conv (k=3) as im2col + GEMM ---
    k_im2col<<<(512 * 3 * 1024) / 256, 256, 0, stream>>>(hidden, ic1, 512, 1024, 3, 2);
    gemm64(stream, ic1, pre_w, pre_b, nullptr, nullptr, conv_out, 512, 1024, 3072, 0);

    // --- transformer input proj ---
    gemm32(stream, conv_out, in_w, in_b, nullptr, nullptr, h, 512, 512, 1024, 0);

    // --- 8 transformer layers ---
    for (int l = 0; l < NL; l++) {
        const float* qw_l = qw + (size_t)l * D_DIM * D_DIM;
        const float* kw_l = kw + (size_t)l * D_DIM * D_DIM;
        const float* vw_l = vw + (size_t)l * D_DIM * D_DIM;
        const float* ow_l = ow + (size_t)l * D_DIM * D_DIM;
        const float* w1_l = w1 + (size_t)l * D_DIM * FF_D;
        const float* w2_l = w2 + (size_t)l * FF_D * D_DIM;

        k_rms<<<512, 256, 0, stream>>>(h, ln1 + l * D_DIM, x, D_DIM);
        k_gemm_qkv<<<dim3(512 / 32, 512 / 64, 3), 256, 0, stream>>>(
            x, qw_l, kw_l, vw_l, qb, kb, vb, 512, 512);
        k_qkrope2<<<dim3(T_LEN * NH, 2), 64, 0, stream>>>(qb, kb, qn + l * HD, kn + l * HD);
        k_attn<<<T_LEN * NH, 256, 0, stream>>>(qb, kb, vb, attnb);
        gemm32(stream, attnb, ow_l, nullptr, h, ls_a + l * D_DIM, h, 512, 512, 512, 0);
        k_rms<<<512, 256, 0, stream>>>(h, ln2 + l * D_DIM, x, D_DIM);
        gemm64(stream, x, w1_l, nullptr, nullptr, nullptr, ff, 512, 2048, 512, 1);
        gemm32(stream, ff, w2_l, nullptr, h, ls_m + l * D_DIM, h, 512, 512, 2048, 0);
    }

    // --- final norm + out proj ---
    k_rms<<<512, 256, 0, stream>>>(h, fn_w, x, D_DIM);
    gemm64(stream, x, out_w, out_b, nullptr, nullptr, houtp, 512, 1024, 512, 0);

    // --- upsample x2 convT, elu fused ---
    k_convT<8><<<dim3(512 / 8, 2, 4), 256, 0, stream>>>(
        houtp, up_w, up_b, up_out, 512, 1024, 1024, 2, 2, 1);

    // --- dec0 conv k=7 SAME as im2col + GEMM (elu fused) ---
    k_im2col<<<(1024 * 7 * 1024) / 256, 256, 0, stream>>>(up_out, ic2, 1024, 1024, 7, 3);
    gemm32(stream, ic2, dec0_w, dec0_b, nullptr, nullptr, dec0_out, 1024, 512, 7168, 2);

    // --- SEANet convT chain ---
    k_convT<8><<<dim3(1024 / 8, 8, 1), 256, 0, stream>>>(
        dec0_out, dw1, db1, t1, 1024, 512, 256, 8, 11, 1);
    k_convT<8><<<dim3(8192 / 16, 6, 1), 256, 0, stream>>>(
        t1, dw2, db2, t2, 8192, 256, 128, 6, 8, 1);
    k_convT<8><<<dim3(49152 / 32, 5, 1), 256, 0, stream>>>(
        t2, dw3, db3, t3, 49152, 128, 64, 5, 7, 1);
    k_convT<8><<<dim3(245760 / 64, 4, 1), 256, 0, stream>>>(
        t3, dw4, db4, t4, 245760, 64, 32, 4, 5, 1);

    // --- final conv ---
    k_conv_fin<<<983040 / 256, 256, 0, stream>>>(t4, fin_w, fin_b, outp, 983040);
}

// Round 3
// 5058.469 us; speedup vs baseline: 1.7281x; 1.2459x over previous
//
#include <hip/hip_runtime.h>
#include <hip/hip_bf16.h>
#include <math.h>

#define T_LEN 512
#define LAT   1024
#define D_DIM 512
#define NH    8
#define HD    64
#define FF_D  2048
#define NL    8
#define NQ    16

// ---------------------------------------------------------------------------
// Workspace layout (float offsets) — static, see host code for map
// ---------------------------------------------------------------------------
#define WS_QFPRE    0
#define WS_G        131072
#define WS_QF       2097152
#define WS_TA       2621440
#define WS_HIDG     3145728            // 2048 guard rows (2 rows) before hidden
#define WS_HID      3147776
#define WS_CONV     3672064
#define WS_H        4196352
#define WS_X        4458496
#define WS_QB       4720640
#define WS_KB       4982784
#define WS_VB       5244928
#define WS_ATT      5507072
#define WS_FF       5769216
#define WS_BSUM     6817792
#define WS_HOUT     6819840            // guard 1024 at 6818816, post at 7344128
#define WS_UP       7348224            // guard 3072 at 7345152, post at 8396800
#define WS_DEC0     8400384            // guard 512  at 8399872, post at 8924672
#define WS_T1       8925440            // guard 256  at 8925184, post at 11022592
#define WS_T2       11022976           // guard 128  at 11022848, post at 17314432
#define WS_W2UP     17314560           // 6291456
#define WS_W2D1     23606016           // 3145728
#define WS_W2D2     26751744           // 589824
#define WS_W2D3     27341568           // 122880
#define WS_T3       31457344           // guard 64 at 31457280, post at 47185984
#define WS_W2D4     47186048           // 24576 -> ends 47210624
#define WS_T4       0                  // aliases phase-A region (dead by then)

// ---------------------------------------------------------------------------
// Zero the guard rows (ws is poisoned 0xAA before every launch)
// ---------------------------------------------------------------------------
__global__ void k_zero_guards(float* __restrict__ ws) {
    const int offs[13] = {3145728, 6818816, 7344128, 7345152, 8396800,
                          8399872, 8924672, 8925184, 11022592, 11022848,
                          17314432, 31457280, 47185984};
    const int lens[13] = {2048, 1024, 1024, 3072, 3072,
                          512, 512, 256, 256, 128,
                          128, 64, 64};
    int r = blockIdx.x;
    for (int i = threadIdx.x; i < lens[r]; i += 256) ws[offs[r] + i] = 0.f;
}

// ---------------------------------------------------------------------------
// Gathers
// ---------------------------------------------------------------------------
__global__ __launch_bounds__(256) void k_gather(const int* __restrict__ codes,
                                                const float* __restrict__ emb_first,
                                                const float* __restrict__ emb_rest,
                                                float* __restrict__ qf_pre,
                                                float* __restrict__ G) {
    int idx = blockIdx.x * 256 + threadIdx.x;
    int c = idx & 255;
    int r = (idx >> 8) & 15;
    int t = idx >> 12;
    if (t >= T_LEN) return;
    if (r == 0) {
        int code = codes[t];
        qf_pre[t * 256 + c] = emb_first[code * 256 + c];
    } else {
        int n = r - 1;
        int code = codes[(n + 1) * T_LEN + t];
        G[t * 3840 + n * 256 + c] = emb_rest[(n * 2048 + code) * 256 + c];
    }
}

__global__ void k_bias_sum(const float* __restrict__ pr_b, float* __restrict__ out) {
    int d = blockIdx.x * 256 + threadIdx.x;
    if (d >= LAT) return;
    float s = 0.f;
    for (int n = 0; n < NQ - 1; n++) s += pr_b[n * LAT + d];
    out[d] = s;
}

// ---------------------------------------------------------------------------
// convT weight transform: W2[(j*Cin+ci), p*Cout+co], j in 0..2 (d=j-1)
//   d==cp  -> w[kk0], d==cp+1 -> w[kk0+s], else 0
// ---------------------------------------------------------------------------
__global__ __launch_bounds__(256) void k_wt(const float* __restrict__ w,
                                            float* __restrict__ W2,
                                            int Cin, int Cout, int s, int pad_a) {
    int idx = blockIdx.x * 256 + threadIdx.x;
    int N = s * Cout;
    int total = 3 * Cin * N;
    if (idx >= total) return;
    int col = idx % N;
    int rowk = idx / N;
    int j = rowk / Cin, ci = rowk % Cin;
    int p = col / Cout, co = col % Cout;
    int kk0 = (pad_a - p) % s;
    if (kk0 < 0) kk0 += s;
    int cp = (p + kk0 - pad_a) / s;
    int d = j - 1;
    float v = 0.f;
    if (d == cp) v = w[((size_t)kk0 * Cin + ci) * Cout + co];
    else if (d == cp + 1) v = w[((size_t)(kk0 + s) * Cin + ci) * Cout + co];
    W2[idx] = v;
}

// ---------------------------------------------------------------------------
// Tiled SGEMM with separate row stride lda (windowed-conv support).
// Tile TM x 64, 256 threads, K-step 16. act: 0 none, 1 gelu, 2 elu.
// bias indexed as bias[col & bmask].
// ---------------------------------------------------------------------------
template <int TM>
__device__ __forceinline__ void gemm_body(const float* __restrict__ A, int lda,
                                          const float* __restrict__ B,
                                          const float* __restrict__ bias, unsigned bmask,
                                          const float* __restrict__ res,
                                          const float* __restrict__ scale,
                                          float* __restrict__ C,
                                          int N, int K, int act, int m0, int n0) {
    __shared__ float As[16][TM + 4];
    __shared__ float Bs[16][64];
    constexpr int RM = TM / 16;
    constexpr int AR = TM * 16 / 256;
    int tid = threadIdx.x;
    int tx = tid & 15, ty = tid >> 4;
    int bc = tid & 63, br0 = tid >> 6;
    float acc[RM][4] = {};
    for (int k0 = 0; k0 < K; k0 += 16) {
#pragma unroll
        for (int i = 0; i < AR; i++) {
            int idx = tid + 256 * i;
            int row = idx >> 4, kk = idx & 15;
            As[kk][row] = A[(size_t)(m0 + row) * lda + k0 + kk];
        }
#pragma unroll
        for (int i = 0; i < 4; i++)
            Bs[br0 + 4 * i][bc] = B[(size_t)(k0 + br0 + 4 * i) * N + n0 + bc];
        __syncthreads();
#pragma unroll
        for (int kk = 0; kk < 16; kk++) {
            float a[RM], b[4];
#pragma unroll
            for (int i = 0; i < RM; i++) a[i] = As[kk][ty * RM + i];
#pragma unroll
            for (int j = 0; j < 4; j++) b[j] = Bs[kk][tx * 4 + j];
#pragma unroll
            for (int i = 0; i < RM; i++)
#pragma unroll
                for (int j = 0; j < 4; j++) acc[i][j] += a[i] * b[j];
        }
        __syncthreads();
    }
#pragma unroll
    for (int i = 0; i < RM; i++) {
        int row = m0 + ty * RM + i;
#pragma unroll
        for (int j = 0; j < 4; j++) {
            int col = n0 + tx * 4 + j;
            float v = acc[i][j];
            if (bias) v += bias[col & bmask];
            if (act == 1) v = 0.5f * v * (1.0f + erff(v * 0.70710678118654752440f));
            else if (act == 2) v = v > 0.f ? v : expm1f(v);
            if (scale) v *= scale[col];
            if (res) v += res[(size_t)row * N + col];
            C[(size_t)row * N + col] = v;
        }
    }
}

template <int TM>
__global__ __launch_bounds__(256) void k_gemm(const float* __restrict__ A, int lda,
                                              const float* __restrict__ B,
                                              const float* __restrict__ bias, unsigned bmask,
                                              const float* __restrict__ res,
                                              const float* __restrict__ scale,
                                              float* __restrict__ C,
                                              int N, int K, int act) {
    gemm_body<TM>(A, lda, B, bias, bmask, res, scale, C, N, K, act,
                  blockIdx.x * TM, blockIdx.y * 64);
}

__global__ __launch_bounds__(256) void k_gemm_qkv(const float* __restrict__ A,
                                                  const float* __restrict__ B0,
                                                  const float* __restrict__ B1,
                                                  const float* __restrict__ B2,
                                                  float* __restrict__ C0,
                                                  float* __restrict__ C1,
                                                  float* __restrict__ C2,
                                                  int N, int K) {
    const float* B = blockIdx.z == 0 ? B0 : (blockIdx.z == 1 ? B1 : B2);
    float* C = blockIdx.z == 0 ? C0 : (blockIdx.z == 1 ? C1 : C2);
    gemm_body<32>(A, K, B, nullptr, 0, nullptr, nullptr, C, N, K, 0,
                  blockIdx.x * 32, blockIdx.y * 64);
}

// ---------------------------------------------------------------------------
// RMSNorm rows of x[M,N]
// ---------------------------------------------------------------------------
__global__ __launch_bounds__(256) void k_rms(const float* __restrict__ x,
                                             const float* __restrict__ g,
                                             float* __restrict__ y, int N) {
    int row = blockIdx.x;
    const float* xr = x + (size_t)row * N;
    int tid = threadIdx.x;
    float s = 0.f;
    for (int i = tid; i < N; i += 256) { float v = xr[i]; s += v * v; }
#pragma unroll
    for (int off = 32; off; off >>= 1) s += __shfl_xor(s, off);
    __shared__ float red[4];
    if ((tid & 63) == 0) red[tid >> 6] = s;
    __syncthreads();
    s = red[0] + red[1] + red[2] + red[3];
    float r = 1.0f / sqrtf(s / (float)N + 1e-6f);
    for (int i = tid; i < N; i += 256) y[(size_t)row * N + i] = xr[i] * r * g[i];
}

// ---------------------------------------------------------------------------
// Fused qk-norm + RoPE for q AND k (blockIdx.y picks buffer)
// ---------------------------------------------------------------------------
__global__ void k_qkrope2(float* __restrict__ q, float* __restrict__ k,
                          const float* __restrict__ gq, const float* __restrict__ gk) {
    int bid = blockIdx.x;
    int t = bid >> 3, h = bid & 7;
    int d = threadIdx.x;
    float* p = (blockIdx.y == 0 ? q : k) + (size_t)t * D_DIM + h * HD;
    const float* g = blockIdx.y == 0 ? gq : gk;
    float val = p[d];
    float s = val * val;
#pragma unroll
    for (int off = 32; off; off >>= 1) s += __shfl_xor(s, off);
    float r = 1.0f / sqrtf(s * (1.0f / 64.0f) + 1e-6f);
    float y = val * r * g[d];
    int dm = d & 31;
    double inv = pow(10000.0, -(double)dm / 32.0);
    double ang = (double)t * inv;
    float c = (float)cos(ang);
    float sn = (float)sin(ang);
    float partner = __shfl_xor(y, 32);
    float out = (d < 32) ? (y * c - partner * sn) : (y * c + partner * sn);
    p[d] = out;
}

// ---------------------------------------------------------------------------
// Causal attention, one block per (t, h)
// ---------------------------------------------------------------------------
__global__ __launch_bounds__(256) void k_attn(const float* __restrict__ q,
                                              const float* __restrict__ k,
                                              const float* __restrict__ v,
                                              float* __restrict__ o) {
    int bid = blockIdx.x;
    int t = bid >> 3, h = bid & 7;
    __shared__ float qs[64];
    __shared__ float sc[T_LEN];
    __shared__ float red[8];
    int tid = threadIdx.x;
    if (tid < 64) qs[tid] = q[(size_t)t * D_DIM + h * HD + tid];
    __syncthreads();
    int nk = t + 1;
    for (int kk = tid; kk < nk; kk += 256) {
        const float* kr = k + (size_t)kk * D_DIM + h * HD;
        float dot = 0.f;
#pragma unroll
        for (int d = 0; d < HD; d++) dot += qs[d] * kr[d];
        sc[kk] = dot * 0.125f;
    }
    __syncthreads();
    float m = -3.4e38f;
    for (int i = tid; i < nk; i += 256) m = fmaxf(m, sc[i]);
#pragma unroll
    for (int off = 32; off; off >>= 1) m = fmaxf(m, __shfl_xor(m, off));
    if ((tid & 63) == 0) red[tid >> 6] = m;
    __syncthreads();
    m = fmaxf(fmaxf(red[0], red[1]), fmaxf(red[2], red[3]));
    float ssum = 0.f;
    for (int i = tid; i < nk; i += 256) { float e = expf(sc[i] - m); sc[i] = e; ssum += e; }
#pragma unroll
    for (int off = 32; off; off >>= 1) ssum += __shfl_xor(ssum, off);
    if ((tid & 63) == 0) red[4 + (tid >> 6)] = ssum;
    __syncthreads();
    ssum = red[4] + red[5] + red[6] + red[7];
    float inv = 1.0f / ssum;
    int d = tid & 63, part = tid >> 6;
    float a0 = 0.f;
    for (int i = part; i < nk; i += 4) a0 += sc[i] * v[(size_t)i * D_DIM + h * HD + d];
    __syncthreads();
    sc[part * 64 + d] = a0;
    __syncthreads();
    if (tid < 64) {
        float r = (sc[tid] + sc[64 + tid] + sc[128 + tid] + sc[192 + tid]) * inv;
        o[(size_t)t * D_DIM + h * HD + tid] = r;
    }
}

// ---------------------------------------------------------------------------
// Final conv: Cin=32 -> 1, K=7 SAME, clip
// ---------------------------------------------------------------------------
__global__ __launch_bounds__(256) void k_conv_fin(const float* __restrict__ x,
                                                  const float* __restrict__ w,
                                                  const float* __restrict__ b,
                                                  float* __restrict__ y, int n) {
    __shared__ float xs[262 * 33];
    __shared__ float wsm[224];
    int tid = threadIdx.x;
    int o0 = blockIdx.x * 256;
    for (int i = tid; i < 262 * 32; i += 256) {
        int r = i >> 5, c = i & 31;
        int t = o0 - 3 + r;
        xs[r * 33 + c] = (t >= 0 && t < n) ? x[(size_t)t * 32 + c] : 0.f;
    }
    if (tid < 224) wsm[tid] = w[tid];
    __syncthreads();
    float acc = b[0];
#pragma unroll
    for (int kk = 0; kk < 7; kk++)
#pragma unroll
        for (int ci = 0; ci < 32; ci++)
            acc += xs[(tid + kk) * 33 + ci] * wsm[kk * 32 + ci];
    y[o0 + tid] = fminf(fmaxf(acc, -1.f), 1.f);
}

// ---------------------------------------------------------------------------
// Host launch
// ---------------------------------------------------------------------------
static inline void gemm64(hipStream_t st, const float* A, int lda, const float* B,
                          const float* bias, unsigned bmask, const float* res,
                          const float* scale, float* C, int M, int N, int K, int act) {
    k_gemm<64><<<dim3(M / 64, N / 64), 256, 0, st>>>(A, lda, B, bias, bmask, res, scale, C, N, K, act);
}
static inline void gemm32(hipStream_t st, const float* A, int lda, const float* B,
                          const float* bias, unsigned bmask, const float* res,
                          const float* scale, float* C, int M, int N, int K, int act) {
    k_gemm<32><<<dim3(M / 32, N / 64), 256, 0, st>>>(A, lda, B, bias, bmask, res, scale, C, N, K, act);
}

extern "C" void kernel_launch(void* const* d_in, const int* in_sizes, int n_in,
                              void* d_out, int out_size, void* d_ws, size_t ws_size,
                              hipStream_t stream) {
    int i = 0;
    const int*   codes     = (const int*)  d_in[i++];
    const float* emb_first = (const float*)d_in[i++];
    const float* pf_w      = (const float*)d_in[i++];
    const float* pf_b      = (const float*)d_in[i++];
    const float* fo_w      = (const float*)d_in[i++];
    const float* fo_b      = (const float*)d_in[i++];
    const float* emb_rest  = (const float*)d_in[i++];
    const float* pr_w      = (const float*)d_in[i++];
    const float* pr_b      = (const float*)d_in[i++];
    const float* ro_w      = (const float*)d_in[i++];
    const float* ro_b      = (const float*)d_in[i++];
    const float* pre_w     = (const float*)d_in[i++];
    const float* pre_b     = (const float*)d_in[i++];
    const float* in_w      = (const float*)d_in[i++];
    const float* in_b      = (const float*)d_in[i++];
    const float* ln1       = (const float*)d_in[i++];
    const float* qw        = (const float*)d_in[i++];
    const float* kw        = (const float*)d_in[i++];
    const float* vw        = (const float*)d_in[i++];
    const float* ow        = (const float*)d_in[i++];
    const float* qn        = (const float*)d_in[i++];
    const float* kn        = (const float*)d_in[i++];
    const float* ls_a      = (const float*)d_in[i++];
    const float* ln2       = (const float*)d_in[i++];
    const float* w1        = (const float*)d_in[i++];
    const float* w2        = (const float*)d_in[i++];
    const float* ls_m      = (const float*)d_in[i++];
    const float* fn_w      = (const float*)d_in[i++];
    const float* out_w     = (const float*)d_in[i++];
    const float* out_b     = (const float*)d_in[i++];
    const float* up_w      = (const float*)d_in[i++];
    const float* up_b      = (const float*)d_in[i++];
    const float* dec0_w    = (const float*)d_in[i++];
    const float* dec0_b    = (const float*)d_in[i++];
    const float* dw1       = (const float*)d_in[i++];
    const float* db1       = (const float*)d_in[i++];
    const float* dw2       = (const float*)d_in[i++];
    const float* db2       = (const float*)d_in[i++];
    const float* dw3       = (const float*)d_in[i++];
    const float* db3       = (const float*)d_in[i++];
    const float* dw4       = (const float*)d_in[i++];
    const float* db4       = (const float*)d_in[i++];
    const float* fin_w     = (const float*)d_in[i++];
    const float* fin_b     = (const float*)d_in[i++];

    float* ws = (float*)d_ws;
    float* outp = (float*)d_out;

    float* qf_pre   = ws + WS_QFPRE;
    float* G        = ws + WS_G;
    float* qf       = ws + WS_QF;
    float* tA       = ws + WS_TA;
    float* hidden   = ws + WS_HID;
    float* conv_out = ws + WS_CONV;
    float* h        = ws + WS_H;
    float* x        = ws + WS_X;
    float* qb       = ws + WS_QB;
    float* kb       = ws + WS_KB;
    float* vb       = ws + WS_VB;
    float* attnb    = ws + WS_ATT;
    float* ff       = ws + WS_FF;
    float* bias_sum = ws + WS_BSUM;
    float* houtp    = ws + WS_HOUT;
    float* up_out   = ws + WS_UP;
    float* dec0_out = ws + WS_DEC0;
    float* t1       = ws + WS_T1;
    float* t2       = ws + WS_T2;
    float* t3       = ws + WS_T3;
    float* t4       = ws + WS_T4;
    float* W2up     = ws + WS_W2UP;
    float* W2d1     = ws + WS_W2D1;
    float* W2d2     = ws + WS_W2D2;
    float* W2d3     = ws + WS_W2D3;
    float* W2d4     = ws + WS_W2D4;

    // --- prep: guards + convT weight transforms (independent of data flow) ---
    k_zero_guards<<<13, 256, 0, stream>>>(ws);
    k_wt<<<24576, 256, 0, stream>>>(up_w, W2up, 1024, 1024, 2, 2);
    k_wt<<<12288, 256, 0, stream>>>(dw1, W2d1, 512, 256, 8, 11);
    k_wt<<<2304, 256, 0, stream>>>(dw2, W2d2, 256, 128, 6, 8);
    k_wt<<<480, 256, 0, stream>>>(dw3, W2d3, 128, 64, 5, 7);
    k_wt<<<96, 256, 0, stream>>>(dw4, W2d4, 64, 32, 4, 5);

    // --- RVQ decode ---
    k_gather<<<8192, 256, 0, stream>>>(codes, emb_first, emb_rest, qf_pre, G);
    k_bias_sum<<<4, 256, 0, stream>>>(pr_b, bias_sum);
    gemm64(stream, qf_pre, 256, pf_w, pf_b, ~0u, nullptr, nullptr, tA, 512, 1024, 256, 0);
    gemm64(stream, tA, 1024, fo_w, fo_b, ~0u, nullptr, nullptr, qf, 512, 1024, 1024, 0);
    gemm64(stream, G, 3840, pr_w, bias_sum, ~0u, nullptr, nullptr, tA, 512, 1024, 3840, 0);
    gemm64(stream, tA, 1024, ro_w, ro_b, ~0u, qf, nullptr, hidden, 512, 1024, 1024, 0);

    // --- causal pre-conv (k=3, left pad 2) via windowed GEMM (lda trick) ---
    gemm64(stream, hidden - 2048, 1024, pre_w, pre_b, ~0u, nullptr, nullptr,
           conv_out, 512, 1024, 3072, 0);

    // --- transformer input proj ---
    gemm32(stream, conv_out, 1024, in_w, in_b, ~0u, nullptr, nullptr, h, 512, 512, 1024, 0);

    // --- 8 transformer layers ---
    for (int l = 0; l < NL; l++) {
        const float* qw_l = qw + (size_t)l * D_DIM * D_DIM;
        const float* kw_l = kw + (size_t)l * D_DIM * D_DIM;
        const float* vw_l = vw + (size_t)l * D_DIM * D_DIM;
        const float* ow_l = ow + (size_t)l * D_DIM * D_DIM;
        const float* w1_l = w1 + (size_t)l * D_DIM * FF_D;
        const float* w2_l = w2 + (size_t)l * FF_D * D_DIM;

        k_rms<<<512, 256, 0, stream>>>(h, ln1 + l * D_DIM, x, D_DIM);
        k_gemm_qkv<<<dim3(512 / 32, 512 / 64, 3), 256, 0, stream>>>(
            x, qw_l, kw_l, vw_l, qb, kb, vb, 512, 512);
        k_qkrope2<<<dim3(T_LEN * NH, 2), 64, 0, stream>>>(qb, kb, qn + l * HD, kn + l * HD);
        k_attn<<<T_LEN * NH, 256, 0, stream>>>(qb, kb, vb, attnb);
        gemm32(stream, attnb, 512, ow_l, nullptr, 0, h, ls_a + l * D_DIM, h, 512, 512, 512, 0);
        k_rms<<<512, 256, 0, stream>>>(h, ln2 + l * D_DIM, x, D_DIM);
        gemm64(stream, x, 512, w1_l, nullptr, 0, nullptr, nullptr, ff, 512, 2048, 512, 1);
        gemm32(stream, ff, 2048, w2_l, nullptr, 0, h, ls_m + l * D_DIM, h, 512, 512, 2048, 0);
    }

    // --- final norm + out proj ---
    k_rms<<<512, 256, 0, stream>>>(h, fn_w, x, D_DIM);
    gemm64(stream, x, 512, out_w, out_b, ~0u, nullptr, nullptr, houtp, 512, 1024, 512, 0);

    // --- upsample x2 convT as GEMM: [512,3072]@[3072,2048], elu ---
    gemm64(stream, houtp - 1024, 1024, W2up, up_b, 1023u, nullptr, nullptr,
           up_out, 512, 2048, 3072, 2);

    // --- dec0 conv k=7 SAME via windowed GEMM, elu ---
    gemm32(stream, up_out - 3072, 1024, dec0_w, dec0_b, ~0u, nullptr, nullptr,
           dec0_out, 1024, 512, 7168, 2);

    // --- SEANet convT chain as GEMMs, elu fused ---
    gemm64(stream, dec0_out - 512, 512, W2d1, db1, 255u, nullptr, nullptr,
           t1, 1024, 2048, 1536, 2);
    gemm64(stream, t1 - 256, 256, W2d2, db2, 127u, nullptr, nullptr,
           t2, 8192, 768, 768, 2);
    gemm64(stream, t2 - 128, 128, W2d3, db3, 63u, nullptr, nullptr,
           t3, 49152, 320, 384, 2);
    gemm64(stream, t3 - 64, 64, W2d4, db4, 31u, nullptr, nullptr,
           t4, 245760, 128, 192, 2);

    // --- final conv ---
    k_conv_fin<<<983040 / 256, 256, 0, stream>>>(t4, fin_w, fin_b, outp, 983040);
}

// Round 4
// 3246.846 us; speedup vs baseline: 2.6923x; 1.5580x over previous
//
#include <hip/hip_runtime.h>
#include <hip/hip_bf16.h>
#include <math.h>

#define T_LEN 512
#define LAT   1024
#define D_DIM 512
#define NH    8
#define HD    64
#define FF_D  2048
#define NL    8
#define NQ    16

// ---------------------------------------------------------------------------
// Workspace layout (float offsets)
// ---------------------------------------------------------------------------
#define WS_QFPRE    0
#define WS_G        131072
#define WS_QF       2097152
#define WS_TA       2621440
#define WS_HIDG     3145728            // 2048 guard floats before hidden
#define WS_HID      3147776
#define WS_CONV     3672064
#define WS_H        4196352
#define WS_X        4458496
#define WS_QB       4720640
#define WS_KB       4982784
#define WS_VB       5244928
#define WS_ATT      5507072
#define WS_FF       5769216
#define WS_BSUM     6817792
#define WS_HOUT     6819840            // guard 1024 at 6818816, post at 7344128
#define WS_UP       7348224            // guard 3072 at 7345152, post at 8396800
#define WS_DEC0     8400384            // guard 512  at 8399872, post at 8924672
#define WS_T1       8925440            // guard 256  at 8925184, post at 11022592
#define WS_T2       11022976           // guard 128  at 11022848, post at 17314432
#define WS_W2UP     17314560           // 6291456
#define WS_W2D1     23606016           // 3145728
#define WS_W2D2     26751744           // 589824
#define WS_W2D3     27341568           // 122880
#define WS_T3       31457344           // guard 64 at 31457280, post at 47185984
#define WS_W2D4     47186048           // 24576 -> ends 47210624
#define WS_T4       0                  // aliases phase-A region (dead by then)
// split-K partials: alias t3 data region (dead until dw3 gemm writes it;
// every partial buffer is consumed by its reduce before the next producer)
#define WS_PART     31457344           // up to 4M floats used

// ---------------------------------------------------------------------------
// Zero the guard rows (ws is poisoned 0xAA before every launch)
// ---------------------------------------------------------------------------
__global__ void k_zero_guards(float* __restrict__ ws) {
    const int offs[13] = {3145728, 6818816, 7344128, 7345152, 8396800,
                          8399872, 8924672, 8925184, 11022592, 11022848,
                          17314432, 31457280, 47185984};
    const int lens[13] = {2048, 1024, 1024, 3072, 3072,
                          512, 512, 256, 256, 128,
                          128, 64, 64};
    int r = blockIdx.x;
    for (int i = threadIdx.x; i < lens[r]; i += 256) ws[offs[r] + i] = 0.f;
}

// ---------------------------------------------------------------------------
// Gathers
// ---------------------------------------------------------------------------
__global__ __launch_bounds__(256) void k_gather(const int* __restrict__ codes,
                                                const float* __restrict__ emb_first,
                                                const float* __restrict__ emb_rest,
                                                float* __restrict__ qf_pre,
                                                float* __restrict__ G) {
    int idx = blockIdx.x * 256 + threadIdx.x;
    int c = idx & 255;
    int r = (idx >> 8) & 15;
    int t = idx >> 12;
    if (t >= T_LEN) return;
    if (r == 0) {
        int code = codes[t];
        qf_pre[t * 256 + c] = emb_first[code * 256 + c];
    } else {
        int n = r - 1;
        int code = codes[(n + 1) * T_LEN + t];
        G[t * 3840 + n * 256 + c] = emb_rest[(n * 2048 + code) * 256 + c];
    }
}

__global__ void k_bias_sum(const float* __restrict__ pr_b, float* __restrict__ out) {
    int d = blockIdx.x * 256 + threadIdx.x;
    if (d >= LAT) return;
    float s = 0.f;
    for (int n = 0; n < NQ - 1; n++) s += pr_b[n * LAT + d];
    out[d] = s;
}

// ---------------------------------------------------------------------------
// convT weight transform (K=2s): W2[(j*Cin+ci), p*Cout+co], j in 0..2 (d=j-1)
// ---------------------------------------------------------------------------
__global__ __launch_bounds__(256) void k_wt(const float* __restrict__ w,
                                            float* __restrict__ W2,
                                            int Cin, int Cout, int s, int pad_a) {
    int idx = blockIdx.x * 256 + threadIdx.x;
    int N = s * Cout;
    int total = 3 * Cin * N;
    if (idx >= total) return;
    int col = idx % N;
    int rowk = idx / N;
    int j = rowk / Cin, ci = rowk % Cin;
    int p = col / Cout, co = col % Cout;
    int kk0 = (pad_a - p) % s;
    if (kk0 < 0) kk0 += s;
    int cp = (p + kk0 - pad_a) / s;
    int d = j - 1;
    float v = 0.f;
    if (d == cp) v = w[((size_t)kk0 * Cin + ci) * Cout + co];
    else if (d == cp + 1) v = w[((size_t)(kk0 + s) * Cin + ci) * Cout + co];
    W2[idx] = v;
}

// ---------------------------------------------------------------------------
// GEMM core: double-buffered LDS, register-staged global loads.
// Tile TM x 64, 256 threads, K-step 16. One barrier per k-step.
// ---------------------------------------------------------------------------
template <int TM>
__device__ __forceinline__ void gemm_core(const float* __restrict__ A, int lda,
                                          const float* __restrict__ B, int N,
                                          int klen, int m0, int n0,
                                          float (&acc)[TM / 16][4]) {
    constexpr int RM = TM / 16;
    constexpr int AR = TM * 16 / 256;
    __shared__ float As[2][16][TM + 4];
    __shared__ float Bs[2][16][64];
    int tid = threadIdx.x;
    int tx = tid & 15, ty = tid >> 4;
    int bc = tid & 63, br0 = tid >> 6;
    int arow[AR], akk[AR];
#pragma unroll
    for (int i = 0; i < AR; i++) { int idx = tid + 256 * i; arow[i] = idx >> 4; akk[i] = idx & 15; }
    float areg[AR], breg[4];
#pragma unroll
    for (int i = 0; i < AR; i++) areg[i] = A[(size_t)(m0 + arow[i]) * lda + akk[i]];
#pragma unroll
    for (int i = 0; i < 4; i++) breg[i] = B[(size_t)(br0 + 4 * i) * N + n0 + bc];
#pragma unroll
    for (int i = 0; i < AR; i++) As[0][akk[i]][arow[i]] = areg[i];
#pragma unroll
    for (int i = 0; i < 4; i++) Bs[0][br0 + 4 * i][bc] = breg[i];
    __syncthreads();
    int nk = klen >> 4;
    for (int t = 0; t < nk; t++) {
        int cur = t & 1;
        if (t + 1 < nk) {
            int k0 = (t + 1) << 4;
#pragma unroll
            for (int i = 0; i < AR; i++) areg[i] = A[(size_t)(m0 + arow[i]) * lda + k0 + akk[i]];
#pragma unroll
            for (int i = 0; i < 4; i++) breg[i] = B[(size_t)(k0 + br0 + 4 * i) * N + n0 + bc];
        }
#pragma unroll
        for (int kk = 0; kk < 16; kk++) {
            float a[RM], b[4];
#pragma unroll
            for (int i = 0; i < RM; i++) a[i] = As[cur][kk][ty * RM + i];
#pragma unroll
            for (int j = 0; j < 4; j++) b[j] = Bs[cur][kk][tx * 4 + j];
#pragma unroll
            for (int i = 0; i < RM; i++)
#pragma unroll
                for (int j = 0; j < 4; j++) acc[i][j] += a[i] * b[j];
        }
        if (t + 1 < nk) {
            int nxt = cur ^ 1;
#pragma unroll
            for (int i = 0; i < AR; i++) As[nxt][akk[i]][arow[i]] = areg[i];
#pragma unroll
            for (int i = 0; i < 4; i++) Bs[nxt][br0 + 4 * i][bc] = breg[i];
            __syncthreads();
        }
    }
}

__device__ __forceinline__ float apply_act(float v, int act) {
    if (act == 1) return 0.5f * v * (1.0f + erff(v * 0.70710678118654752440f));
    if (act == 2) return v > 0.f ? v : expm1f(v);
    return v;
}

// If part != null: raw partial write to part + z*mn (epilogue done in k_reduce).
template <int TM>
__global__ __launch_bounds__(256) void k_gemm2(const float* __restrict__ A, int lda,
                                               const float* __restrict__ B,
                                               const float* __restrict__ bias, unsigned bmask,
                                               const float* __restrict__ res,
                                               const float* __restrict__ scale,
                                               float* __restrict__ C,
                                               float* __restrict__ part, long mn,
                                               int N, int klen, int act) {
    constexpr int RM = TM / 16;
    float acc[RM][4] = {};
    int m0 = blockIdx.x * TM, n0 = blockIdx.y * 64;
    int kz = blockIdx.z * klen;
    gemm_core<TM>(A + kz, lda, B + (size_t)kz * N, N, klen, m0, n0, acc);
    int tid = threadIdx.x;
    int tx = tid & 15, ty = tid >> 4;
    if (part) {
        float* out = part + (size_t)blockIdx.z * mn;
#pragma unroll
        for (int i = 0; i < RM; i++)
#pragma unroll
            for (int j = 0; j < 4; j++)
                out[(size_t)(m0 + ty * RM + i) * N + n0 + tx * 4 + j] = acc[i][j];
    } else {
#pragma unroll
        for (int i = 0; i < RM; i++) {
            int row = m0 + ty * RM + i;
#pragma unroll
            for (int j = 0; j < 4; j++) {
                int col = n0 + tx * 4 + j;
                float v = acc[i][j];
                if (bias) v += bias[col & bmask];
                v = apply_act(v, act);
                if (scale) v *= scale[col];
                if (res) v += res[(size_t)row * N + col];
                C[(size_t)row * N + col] = v;
            }
        }
    }
}

// Fused QKV with split-K=2: z = which*2 + s; raw partials.
__global__ __launch_bounds__(256) void k_qkv(const float* __restrict__ A,
                                             const float* __restrict__ B0,
                                             const float* __restrict__ B1,
                                             const float* __restrict__ B2,
                                             float* __restrict__ part) {
    int which = blockIdx.z >> 1, s = blockIdx.z & 1;
    const float* B = which == 0 ? B0 : (which == 1 ? B1 : B2);
    float acc[2][4] = {};
    int m0 = blockIdx.x * 32, n0 = blockIdx.y * 64;
    int kz = s * 256;
    gemm_core<32>(A + kz, 512, B + (size_t)kz * 512, 512, 256, m0, n0, acc);
    int tid = threadIdx.x;
    int tx = tid & 15, ty = tid >> 4;
    float* out = part + (size_t)blockIdx.z * (512 * 512);
#pragma unroll
    for (int i = 0; i < 2; i++)
#pragma unroll
        for (int j = 0; j < 4; j++)
            out[(size_t)(m0 + ty * 2 + i) * 512 + n0 + tx * 4 + j] = acc[i][j];
}

// ---------------------------------------------------------------------------
// Split-K reduce + epilogue (bias -> act -> scale -> res)
// ---------------------------------------------------------------------------
__global__ __launch_bounds__(256) void k_reduce(const float* __restrict__ part, long mn, int S,
                                                const float* __restrict__ bias, unsigned bmask,
                                                const float* __restrict__ res,
                                                const float* __restrict__ scale,
                                                float* __restrict__ C, int N, int act) {
    long idx = ((long)blockIdx.x * 256 + threadIdx.x) * 4;
    if (idx >= mn) return;
    float4 v = *(const float4*)(part + idx);
    for (int s2 = 1; s2 < S; s2++) {
        float4 u = *(const float4*)(part + (size_t)s2 * mn + idx);
        v.x += u.x; v.y += u.y; v.z += u.z; v.w += u.w;
    }
    int col = (int)(idx % N);
    float vv[4] = {v.x, v.y, v.z, v.w};
#pragma unroll
    for (int j = 0; j < 4; j++) {
        float t = vv[j];
        int c = col + j;
        if (bias) t += bias[c & bmask];
        t = apply_act(t, act);
        if (scale) t *= scale[c];
        if (res) t += res[idx + j];
        vv[j] = t;
    }
    *(float4*)(C + idx) = make_float4(vv[0], vv[1], vv[2], vv[3]);
}

__global__ __launch_bounds__(256) void k_reduce_qkv(const float* __restrict__ part,
                                                    float* __restrict__ q,
                                                    float* __restrict__ k,
                                                    float* __restrict__ v) {
    const long mn = 262144;
    int w = blockIdx.y;
    long idx = ((long)blockIdx.x * 256 + threadIdx.x) * 4;
    float4 a = *(const float4*)(part + (size_t)(2 * w) * mn + idx);
    float4 b = *(const float4*)(part + (size_t)(2 * w + 1) * mn + idx);
    float* C = w == 0 ? q : (w == 1 ? k : v);
    *(float4*)(C + idx) = make_float4(a.x + b.x, a.y + b.y, a.z + b.z, a.w + b.w);
}

// ---------------------------------------------------------------------------
// RMSNorm rows of x[M,N]
// ---------------------------------------------------------------------------
__global__ __launch_bounds__(256) void k_rms(const float* __restrict__ x,
                                             const float* __restrict__ g,
                                             float* __restrict__ y, int N) {
    int row = blockIdx.x;
    const float* xr = x + (size_t)row * N;
    int tid = threadIdx.x;
    float s = 0.f;
    for (int i = tid; i < N; i += 256) { float v = xr[i]; s += v * v; }
#pragma unroll
    for (int off = 32; off; off >>= 1) s += __shfl_xor(s, off);
    __shared__ float red[4];
    if ((tid & 63) == 0) red[tid >> 6] = s;
    __syncthreads();
    s = red[0] + red[1] + red[2] + red[3];
    float r = 1.0f / sqrtf(s / (float)N + 1e-6f);
    for (int i = tid; i < N; i += 256) y[(size_t)row * N + i] = xr[i] * r * g[i];
}

// ---------------------------------------------------------------------------
// Fused qk-norm + RoPE for q AND k (blockIdx.y picks buffer)
// ---------------------------------------------------------------------------
__global__ void k_qkrope2(float* __restrict__ q, float* __restrict__ k,
                          const float* __restrict__ gq, const float* __restrict__ gk) {
    int bid = blockIdx.x;
    int t = bid >> 3, h = bid & 7;
    int d = threadIdx.x;
    float* p = (blockIdx.y == 0 ? q : k) + (size_t)t * D_DIM + h * HD;
    const float* g = blockIdx.y == 0 ? gq : gk;
    float val = p[d];
    float s = val * val;
#pragma unroll
    for (int off = 32; off; off >>= 1) s += __shfl_xor(s, off);
    float r = 1.0f / sqrtf(s * (1.0f / 64.0f) + 1e-6f);
    float y = val * r * g[d];
    int dm = d & 31;
    double inv = pow(10000.0, -(double)dm / 32.0);
    double ang = (double)t * inv;
    float c = (float)cos(ang);
    float sn = (float)sin(ang);
    float partner = __shfl_xor(y, 32);
    float out = (d < 32) ? (y * c - partner * sn) : (y * c + partner * sn);
    p[d] = out;
}

// ---------------------------------------------------------------------------
// Causal attention, one block per (t, h)
// ---------------------------------------------------------------------------
__global__ __launch_bounds__(256) void k_attn(const float* __restrict__ q,
                                              const float* __restrict__ k,
                                              const float* __restrict__ v,
                                              float* __restrict__ o) {
    int bid = blockIdx.x;
    int t = bid >> 3, h = bid & 7;
    __shared__ float qs[64];
    __shared__ float sc[T_LEN];
    __shared__ float red[8];
    int tid = threadIdx.x;
    if (tid < 64) qs[tid] = q[(size_t)t * D_DIM + h * HD + tid];
    __syncthreads();
    int nk = t + 1;
    for (int kk = tid; kk < nk; kk += 256) {
        const float* kr = k + (size_t)kk * D_DIM + h * HD;
        float dot = 0.f;
#pragma unroll
        for (int d = 0; d < HD; d++) dot += qs[d] * kr[d];
        sc[kk] = dot * 0.125f;
    }
    __syncthreads();
    float m = -3.4e38f;
    for (int i = tid; i < nk; i += 256) m = fmaxf(m, sc[i]);
#pragma unroll
    for (int off = 32; off; off >>= 1) m = fmaxf(m, __shfl_xor(m, off));
    if ((tid & 63) == 0) red[tid >> 6] = m;
    __syncthreads();
    m = fmaxf(fmaxf(red[0], red[1]), fmaxf(red[2], red[3]));
    float ssum = 0.f;
    for (int i = tid; i < nk; i += 256) { float e = expf(sc[i] - m); sc[i] = e; ssum += e; }
#pragma unroll
    for (int off = 32; off; off >>= 1) ssum += __shfl_xor(ssum, off);
    if ((tid & 63) == 0) red[4 + (tid >> 6)] = ssum;
    __syncthreads();
    ssum = red[4] + red[5] + red[6] + red[7];
    float inv = 1.0f / ssum;
    int d = tid & 63, part = tid >> 6;
    float a0 = 0.f;
    for (int i = part; i < nk; i += 4) a0 += sc[i] * v[(size_t)i * D_DIM + h * HD + d];
    __syncthreads();
    sc[part * 64 + d] = a0;
    __syncthreads();
    if (tid < 64) {
        float r = (sc[tid] + sc[64 + tid] + sc[128 + tid] + sc[192 + tid]) * inv;
        o[(size_t)t * D_DIM + h * HD + tid] = r;
    }
}

// ---------------------------------------------------------------------------
// Final conv: Cin=32 -> 1, K=7 SAME, clip
// ---------------------------------------------------------------------------
__global__ __launch_bounds__(256) void k_conv_fin(const float* __restrict__ x,
                                                  const float* __restrict__ w,
                                                  const float* __restrict__ b,
                                                  float* __restrict__ y, int n) {
    __shared__ float xs[262 * 33];
    __shared__ float wsm[224];
    int tid = threadIdx.x;
    int o0 = blockIdx.x * 256;
    for (int i = tid; i < 262 * 32; i += 256) {
        int r = i >> 5, c = i & 31;
        int t = o0 - 3 + r;
        xs[r * 33 + c] = (t >= 0 && t < n) ? x[(size_t)t * 32 + c] : 0.f;
    }
    if (tid < 224) wsm[tid] = w[tid];
    __syncthreads();
    float acc = b[0];
#pragma unroll
    for (int kk = 0; kk < 7; kk++)
#pragma unroll
        for (int ci = 0; ci < 32; ci++)
            acc += xs[(tid + kk) * 33 + ci] * wsm[kk * 32 + ci];
    y[o0 + tid] = fminf(fmaxf(acc, -1.f), 1.f);
}

// ---------------------------------------------------------------------------
// Host helpers
// ---------------------------------------------------------------------------
static inline void gemmS64(hipStream_t st, const float* A, int lda, const float* B,
                           const float* bias, unsigned bmask, const float* res,
                           const float* scale, float* C, float* part,
                           int M, int N, int K, int S, int act) {
    long mn = (long)M * N;
    if (S > 1) {
        k_gemm2<64><<<dim3(M / 64, N / 64, S), 256, 0, st>>>(
            A, lda, B, nullptr, 0, nullptr, nullptr, nullptr, part, mn, N, K / S, 0);
        k_reduce<<<dim3((int)(mn / 1024)), 256, 0, st>>>(
            part, mn, S, bias, bmask, res, scale, C, N, act);
    } else {
        k_gemm2<64><<<dim3(M / 64, N / 64, 1), 256, 0, st>>>(
            A, lda, B, bias, bmask, res, scale, C, nullptr, mn, N, K, act);
    }
}
static inline void gemmS32(hipStream_t st, const float* A, int lda, const float* B,
                           const float* bias, unsigned bmask, const float* res,
                           const float* scale, float* C, float* part,
                           int M, int N, int K, int S, int act) {
    long mn = (long)M * N;
    if (S > 1) {
        k_gemm2<32><<<dim3(M / 32, N / 64, S), 256, 0, st>>>(
            A, lda, B, nullptr, 0, nullptr, nullptr, nullptr, part, mn, N, K / S, 0);
        k_reduce<<<dim3((int)(mn / 1024)), 256, 0, st>>>(
            part, mn, S, bias, bmask, res, scale, C, N, act);
    } else {
        k_gemm2<32><<<dim3(M / 32, N / 64, 1), 256, 0, st>>>(
            A, lda, B, bias, bmask, res, scale, C, nullptr, mn, N, K, act);
    }
}

extern "C" void kernel_launch(void* const* d_in, const int* in_sizes, int n_in,
                              void* d_out, int out_size, void* d_ws, size_t ws_size,
                              hipStream_t stream) {
    int i = 0;
    const int*   codes     = (const int*)  d_in[i++];
    const float* emb_first = (const float*)d_in[i++];
    const float* pf_w      = (const float*)d_in[i++];
    const float* pf_b      = (const float*)d_in[i++];
    const float* fo_w      = (const float*)d_in[i++];
    const float* fo_b      = (const float*)d_in[i++];
    const float* emb_rest  = (const float*)d_in[i++];
    const float* pr_w      = (const float*)d_in[i++];
    const float* pr_b      = (const float*)d_in[i++];
    const float* ro_w      = (const float*)d_in[i++];
    const float* ro_b      = (const float*)d_in[i++];
    const float* pre_w     = (const float*)d_in[i++];
    const float* pre_b     = (const float*)d_in[i++];
    const float* in_w      = (const float*)d_in[i++];
    const float* in_b      = (const float*)d_in[i++];
    const float* ln1       = (const float*)d_in[i++];
    const float* qw        = (const float*)d_in[i++];
    const float* kw        = (const float*)d_in[i++];
    const float* vw        = (const float*)d_in[i++];
    const float* ow        = (const float*)d_in[i++];
    const float* qn        = (const float*)d_in[i++];
    const float* kn        = (const float*)d_in[i++];
    const float* ls_a      = (const float*)d_in[i++];
    const float* ln2       = (const float*)d_in[i++];
    const float* w1        = (const float*)d_in[i++];
    const float* w2        = (const float*)d_in[i++];
    const float* ls_m      = (const float*)d_in[i++];
    const float* fn_w      = (const float*)d_in[i++];
    const float* out_w     = (const float*)d_in[i++];
    const float* out_b     = (const float*)d_in[i++];
    const float* up_w      = (const float*)d_in[i++];
    const float* up_b      = (const float*)d_in[i++];
    const float* dec0_w    = (const float*)d_in[i++];
    const float* dec0_b    = (const float*)d_in[i++];
    const float* dw1       = (const float*)d_in[i++];
    const float* db1       = (const float*)d_in[i++];
    const float* dw2       = (const float*)d_in[i++];
    const float* db2       = (const float*)d_in[i++];
    const float* dw3       = (const float*)d_in[i++];
    const float* db3       = (const float*)d_in[i++];
    const float* dw4       = (const float*)d_in[i++];
    const float* db4       = (const float*)d_in[i++];
    const float* fin_w     = (const float*)d_in[i++];
    const float* fin_b     = (const float*)d_in[i++];

    float* ws = (float*)d_ws;
    float* outp = (float*)d_out;

    float* qf_pre   = ws + WS_QFPRE;
    float* G        = ws + WS_G;
    float* qf       = ws + WS_QF;
    float* tA       = ws + WS_TA;
    float* hidden   = ws + WS_HID;
    float* conv_out = ws + WS_CONV;
    float* h        = ws + WS_H;
    float* x        = ws + WS_X;
    float* qb       = ws + WS_QB;
    float* kb       = ws + WS_KB;
    float* vb       = ws + WS_VB;
    float* attnb    = ws + WS_ATT;
    float* ff       = ws + WS_FF;
    float* bias_sum = ws + WS_BSUM;
    float* houtp    = ws + WS_HOUT;
    float* up_out   = ws + WS_UP;
    float* dec0_out = ws + WS_DEC0;
    float* t1       = ws + WS_T1;
    float* t2       = ws + WS_T2;
    float* t3       = ws + WS_T3;
    float* t4       = ws + WS_T4;
    float* W2up     = ws + WS_W2UP;
    float* W2d1     = ws + WS_W2D1;
    float* W2d2     = ws + WS_W2D2;
    float* W2d3     = ws + WS_W2D3;
    float* W2d4     = ws + WS_W2D4;
    float* part     = ws + WS_PART;

    // --- prep ---
    k_zero_guards<<<13, 256, 0, stream>>>(ws);
    k_wt<<<24576, 256, 0, stream>>>(up_w, W2up, 1024, 1024, 2, 2);
    k_wt<<<12288, 256, 0, stream>>>(dw1, W2d1, 512, 256, 8, 11);
    k_wt<<<2304, 256, 0, stream>>>(dw2, W2d2, 256, 128, 6, 8);
    k_wt<<<480, 256, 0, stream>>>(dw3, W2d3, 128, 64, 5, 7);
    k_wt<<<96, 256, 0, stream>>>(dw4, W2d4, 64, 32, 4, 5);

    // --- RVQ decode ---
    k_gather<<<8192, 256, 0, stream>>>(codes, emb_first, emb_rest, qf_pre, G);
    k_bias_sum<<<4, 256, 0, stream>>>(pr_b, bias_sum);
    gemmS64(stream, qf_pre, 256, pf_w, pf_b, ~0u, nullptr, nullptr, tA, part, 512, 1024, 256, 2, 0);
    gemmS64(stream, tA, 1024, fo_w, fo_b, ~0u, nullptr, nullptr, qf, part, 512, 1024, 1024, 4, 0);
    gemmS64(stream, G, 3840, pr_w, bias_sum, ~0u, nullptr, nullptr, tA, part, 512, 1024, 3840, 8, 0);
    gemmS64(stream, tA, 1024, ro_w, ro_b, ~0u, qf, nullptr, hidden, part, 512, 1024, 1024, 4, 0);

    // --- causal pre-conv (k=3) via windowed GEMM ---
    gemmS64(stream, hidden - 2048, 1024, pre_w, pre_b, ~0u, nullptr, nullptr,
            conv_out, part, 512, 1024, 3072, 8, 0);

    // --- transformer input proj ---
    gemmS32(stream, conv_out, 1024, in_w, in_b, ~0u, nullptr, nullptr, h, part, 512, 512, 1024, 4, 0);

    // --- 8 transformer layers ---
    for (int l = 0; l < NL; l++) {
        const float* qw_l = qw + (size_t)l * D_DIM * D_DIM;
        const float* kw_l = kw + (size_t)l * D_DIM * D_DIM;
        const float* vw_l = vw + (size_t)l * D_DIM * D_DIM;
        const float* ow_l = ow + (size_t)l * D_DIM * D_DIM;
        const float* w1_l = w1 + (size_t)l * D_DIM * FF_D;
        const float* w2_l = w2 + (size_t)l * FF_D * D_DIM;

        k_rms<<<512, 256, 0, stream>>>(h, ln1 + l * D_DIM, x, D_DIM);
        k_qkv<<<dim3(16, 8, 6), 256, 0, stream>>>(x, qw_l, kw_l, vw_l, part);
        k_reduce_qkv<<<dim3(256, 3), 256, 0, stream>>>(part, qb, kb, vb);
        k_qkrope2<<<dim3(T_LEN * NH, 2), 64, 0, stream>>>(qb, kb, qn + l * HD, kn + l * HD);
        k_attn<<<T_LEN * NH, 256, 0, stream>>>(qb, kb, vb, attnb);
        gemmS32(stream, attnb, 512, ow_l, nullptr, 0, h, ls_a + l * D_DIM, h, part,
                512, 512, 512, 2, 0);
        k_rms<<<512, 256, 0, stream>>>(h, ln2 + l * D_DIM, x, D_DIM);
        gemmS64(stream, x, 512, w1_l, nullptr, 0, nullptr, nullptr, ff, part,
                512, 2048, 512, 2, 1);
        gemmS32(stream, ff, 2048, w2_l, nullptr, 0, h, ls_m + l * D_DIM, h, part,
                512, 512, 2048, 8, 0);
    }

    // --- final norm + out proj ---
    k_rms<<<512, 256, 0, stream>>>(h, fn_w, x, D_DIM);
    gemmS64(stream, x, 512, out_w, out_b, ~0u, nullptr, nullptr, houtp, part, 512, 1024, 512, 4, 0);

    // --- upsample x2 convT as GEMM, elu ---
    gemmS64(stream, houtp - 1024, 1024, W2up, up_b, 1023u, nullptr, nullptr,
            up_out, part, 512, 2048, 3072, 4, 2);

    // --- dec0 conv k=7 SAME via windowed GEMM, elu ---
    gemmS32(stream, up_out - 3072, 1024, dec0_w, dec0_b, ~0u, nullptr, nullptr,
            dec0_out, part, 1024, 512, 7168, 4, 2);

    // --- SEANet convT chain as GEMMs, elu ---
    gemmS64(stream, dec0_out - 512, 512, W2d1, db1, 255u, nullptr, nullptr,
            t1, part, 1024, 2048, 1536, 2, 2);
    gemmS64(stream, t1 - 256, 256, W2d2, db2, 127u, nullptr, nullptr,
            t2, nullptr, 8192, 768, 768, 1, 2);
    gemmS64(stream, t2 - 128, 128, W2d3, db3, 63u, nullptr, nullptr,
            t3, nullptr, 49152, 320, 384, 1, 2);
    gemmS64(stream, t3 - 64, 64, W2d4, db4, 31u, nullptr, nullptr,
            t4, nullptr, 245760, 128, 192, 1, 2);

    // --- final conv ---
    k_conv_fin<<<983040 / 256, 256, 0, stream>>>(t4, fin_w, fin_b, outp, 983040);
}